// Round 6
// baseline (208.246 us; speedup 1.0000x reference)
//
#include <hip/hip_runtime.h>

// NPZD plankton ODE: B*WK = 106496 independent trajectories, 56 Euler steps.
//
// R12: R11's split measured a PURE streaming kernel at 60 us (3.2 TB/s,
// half of copy BW) and paid 95 MB of intermediate traffic on top -> split
// is a dead end; burst-then-drain staging is capped at ~half BW no matter
// what. Minimum traffic = 143 MB read (every line holds stride-3 words) +
// 13 MB write ~= 25 us. The entire LDS-transpose apparatus exists only to
// coalesce reads, and its phase coupling has cost ~2x in every round.
// Fix: DELETE it. Lane = week gathers its own trajectory data directly
// from global: per 4 steps, 3 consecutive f4 (48 B) per array at the
// lane's week base (stride 672 B across lanes; every line still fetched
// exactly once), extracting the R7-proven group-of-12 words
// {f4_0.x, f4_0.w, f4_1.z, f4_2.y}. Double-buffered: issue group g+1's
// 6 dwordx4 (each instr alone puts ~52 lines in flight -> MSHR-saturating),
// integrate group g, repeat. No LDS, no barriers, no compact VALU, no
// intermediate; the miss queue never drains. Unlike the original R1-R4
// stride-gather (per-step scalar loads, zero prefetch), this keeps a
// full group of requests outstanding for the wave's entire lifetime.

typedef float f32x4 __attribute__((ext_vector_type(4)));

#define NPZD_B 2048
#define NPZD_WK 52
#define NPZD_HRS 8760

__global__ __launch_bounds__(64, 2) void npzd_kernel(
    const float* __restrict__ X_in,     // (B, WK, 5, 1)
    const float* __restrict__ gf,       // (B, HRS)
    const float* __restrict__ gm,       // (B, HRS)
    const float* __restrict__ params,   // (B, 10)
    const float* __restrict__ dt_ptr,   // scalar
    float* __restrict__ out)            // (B, WK, 4, 8)
{
    const int b    = blockIdx.x;
    const int lane = threadIdx.x;
    const int w    = (lane < NPZD_WK) ? lane : (NPZD_WK - 1);   // dup lanes: L1 hits, store-masked

    // per-lane week base: 168 words = 42 f4 per week. All 14 groups are
    // reachable via 13-bit immediate offsets from this one base (max 41*16B).
    const f32x4* __restrict__ gfw = (const f32x4*)(gf + (size_t)b * NPZD_HRS) + 42 * w;
    const f32x4* __restrict__ gmw = (const f32x4*)(gm + (size_t)b * NPZD_HRS) + 42 * w;

    // ---- prefetch group 0 (6 loads in flight) ----
    f32x4 fA0 = gfw[0], fA1 = gfw[1], fA2 = gfw[2];
    f32x4 mA0 = gmw[0], mA1 = gmw[1], mA2 = gmw[2];
    f32x4 fB0, fB1, fB2, mB0, mB1, mB2;

    // hoisted scalars overlap the first group's latency
    const float dt = dt_ptr[0];   // 0.125
    const float* xb = X_in + ((size_t)b * NPZD_WK + w) * 5;
    float N = xb[1], P = xb[2], Z = xb[3], D = xb[4];

    const float* pp = params + (size_t)b * 10;   // block-uniform -> s_load
    const float chi   = pp[0];
    const float rho2  = pp[1] * 2.0f;
    const float gam1  = pp[2] * 0.1f;
    const float lam05 = pp[3] * 0.05f;
    const float eps1  = pp[4] * 0.1f;
    const float alp3  = pp[5] * 0.3f;
    const float bet6  = pp[6] * 0.6f;
    const float eta15 = pp[7] * 0.15f;
    const float phi4  = pp[8] * 0.4f;
    const float zet1  = pp[9] * 0.1f;
    const float rem   = 1.0f - alp3 - bet6;

    float oN[8], oP[8], oZ[8], oD[8];
    oN[0] = N; oP[0] = P; oZ[0] = Z; oD[0] = D;

    #pragma unroll
    for (int g = 0; g < 14; ++g) {
        const bool even = (g & 1) == 0;   // compile-time after full unroll

        // ---- issue group g+1 into the other buffer BEFORE consuming g ----
        if (g < 13) {
            const f32x4* pf = gfw + 3 * (g + 1);
            const f32x4* pm = gmw + 3 * (g + 1);
            if (even) {
                fB0 = pf[0]; fB1 = pf[1]; fB2 = pf[2];
                mB0 = pm[0]; mB1 = pm[1]; mB2 = pm[2];
            } else {
                fA0 = pf[0]; fA1 = pf[1]; fA2 = pf[2];
                mA0 = pm[0]; mA1 = pm[1]; mA2 = pm[2];
            }
        }

        // ---- integrate 4 steps from group g ----
        // group g = week-words 12g..12g+11; steps 4g+q use word 12g+3q:
        // q=0 -> f4_0.x, q=1 -> f4_0.w, q=2 -> f4_1.z, q=3 -> f4_2.y (R7-proven).
        const f32x4 cf0 = even ? fA0 : fB0;
        const f32x4 cf1 = even ? fA1 : fB1;
        const f32x4 cf2 = even ? fA2 : fB2;
        const f32x4 cm0 = even ? mA0 : mB0;
        const f32x4 cm1 = even ? mA1 : mB1;
        const f32x4 cm2 = even ? mA2 : mB2;
        const float fs[4] = {cf0.x, cf0.w, cf1.z, cf2.y};
        const float ms[4] = {cm0.x, cm0.w, cm1.z, cm2.y};

        #pragma unroll
        for (int q = 0; q < 4; ++q) {
            const float ft = fs[q], mt = ms[q];
            const float Pc = fmaxf(0.01f, P);
            const float Zc = fmaxf(0.01f, Z);
            const float gN = N * __builtin_amdgcn_rcpf(chi + N);
            const float zg = rho2 * (1.0f - __expf(-lam05 * Pc)) * Zc;
            const float up = gN * ft * Pc;
            const float Nn = N + dt * (-up + alp3 * zg + eps1 * P + gam1 * Z + phi4 * D + mt * (8.0f - N));
            const float Pn = P + dt * (up - zg - eps1 * P - eta15 * P - mt * P);
            const float Zn = Z + dt * (bet6 * zg - gam1 * Z - mt * Z);
            const float Dn = D + dt * (eta15 * P + rem * zg - phi4 * D - zet1 * D - mt * D);
            N = Nn; P = Pn; Z = Zn; D = Dn;
        }
        if (g & 1) {   // after steps 7,15,...,55 (sampled: states 8,16,...,56)
            const int c = (g >> 1) + 1;
            oN[c] = N; oP[c] = P; oZ[c] = Z; oD[c] = D;
        }
    }

    // ---- output: (b, w, state, 8) -> 32 contiguous floats per trajectory ----
    if (lane >= NPZD_WK) return;
    f32x4* o4 = (f32x4*)(out + ((size_t)b * NPZD_WK + w) * 32);
    o4[0] = (f32x4){oN[0], oN[1], oN[2], oN[3]};
    o4[1] = (f32x4){oN[4], oN[5], oN[6], oN[7]};
    o4[2] = (f32x4){oP[0], oP[1], oP[2], oP[3]};
    o4[3] = (f32x4){oP[4], oP[5], oP[6], oP[7]};
    o4[4] = (f32x4){oZ[0], oZ[1], oZ[2], oZ[3]};
    o4[5] = (f32x4){oZ[4], oZ[5], oZ[6], oZ[7]};
    o4[6] = (f32x4){oD[0], oD[1], oD[2], oD[3]};
    o4[7] = (f32x4){oD[4], oD[5], oD[6], oD[7]};
}

extern "C" void kernel_launch(void* const* d_in, const int* in_sizes, int n_in,
                              void* d_out, int out_size, void* d_ws, size_t ws_size,
                              hipStream_t stream) {
    const float* X_in   = (const float*)d_in[0];
    const float* gf     = (const float*)d_in[1];
    const float* gm     = (const float*)d_in[2];
    const float* params = (const float*)d_in[3];
    const float* dt_ptr = (const float*)d_in[4];
    float* out = (float*)d_out;

    npzd_kernel<<<NPZD_B, 64, 0, stream>>>(X_in, gf, gm, params, dt_ptr, out);
}

// Round 8
// 183.060 us; speedup vs baseline: 1.1376x; 1.1376x over previous
//
#include <hip/hip_runtime.h>

// NPZD plankton ODE: B*WK = 106496 independent trajectories, 56 Euler steps.
//
// R14: R13's asm register pipeline corrupted data (absmax 694): the
// compiler treats asm loads as completed at the statement, so regalloc
// copies/spills of still-pending destinations capture garbage. Register
// pipelines are dead both ways (hipcc collapses visible ones: VGPR 64/44/40
// across R7/11/12; corrupts hidden ones: R13).
// Fix: keep the in-flight window in the DMA QUEUE, not registers.
// global_load_lds is fire-and-forget (no dest VGPR -> allocator can't
// collapse or corrupt it) and R10 proved the builtin correct here
// (absmax 4.0); R10's perf failure was its SCATTERED sources. So make
// every DMA lane-contiguous (m97 fast path): stage the RAW row image.
//   block = 1 wave = 13 weeks (546 f4, f4-aligned). 18 DMAs of 1 KB
//   (9/array, 64 lanes x 16 B contiguous), all issued up front;
//   X_in/params loads overlap; one __syncthreads() (compiler emits
//   vmcnt(0)); lanes 0..12 integrate from the raw image (word 168*wl+3s,
//   R10-proven); 13.3 MB coalesced output.
// LDS 18 KB -> 8 independent wave-blocks/CU, grid 8192: ~144 DMA instrs
// (~2300 lines) of per-CU backlog across desynced waves -> the miss queue
// cannot drain while any wave has backlog. The R2-R12 duty-cycle trap and
// the R13 register hazard are both structurally impossible here.

typedef float f32x4 __attribute__((ext_vector_type(4)));

#define NPZD_B 2048
#define NPZD_WK 52
#define NPZD_HRS 8760
#define NPZD_QW 13             // weeks per block (quarter batch)
#define NPZD_QF4 546           // f4 per array per block = 13*42 (f4-aligned)
#define NPZD_PF4 576           // padded to 9 DMA instrs x 64 lanes
#define NPZD_MAXF4 2189        // last valid f4 of a row (clamp target)

typedef const __attribute__((address_space(1))) void* gas_t;
typedef __attribute__((address_space(3))) void* las_t;

__global__ __launch_bounds__(64) void npzd_kernel(
    const float* __restrict__ X_in,     // (B, WK, 5, 1)
    const float* __restrict__ gf,       // (B, HRS)
    const float* __restrict__ gm,       // (B, HRS)
    const float* __restrict__ params,   // (B, 10)
    const float* __restrict__ dt_ptr,   // scalar
    float* __restrict__ out)            // (B, WK, 4, 8)
{
    __shared__ __align__(16) f32x4 lf4[NPZD_PF4];   // 9216 B
    __shared__ __align__(16) f32x4 lm4[NPZD_PF4];   // 9216 B

    const int bid  = blockIdx.x;
    const int b    = bid >> 2;
    const int qb   = bid & 3;            // weeks [13*qb, 13*qb+13)
    const int lane = threadIdx.x;

    const f32x4* __restrict__ gf4 = (const f32x4*)(gf + (size_t)b * NPZD_HRS);
    const f32x4* __restrict__ gm4 = (const f32x4*)(gm + (size_t)b * NPZD_HRS);

    // ---- issue 18 fire-and-forget DMAs, each 64 lanes x 16 B contiguous ----
    // raw image: lds f4 slot (i*64+lane) <- row f4 (546*qb + i*64 + lane).
    // Only qb==3 can run past the row (max 2213 > 2189): clamp -> dup lines
    // into the pad slots, never consumed.
    const int base = NPZD_QF4 * qb;
    #pragma unroll
    for (int i = 0; i < 9; ++i) {
        int idx = base + i * 64 + lane;
        if (idx > NPZD_MAXF4) idx = NPZD_MAXF4;
        __builtin_amdgcn_global_load_lds((gas_t)(const void*)(gf4 + idx),
                                         (las_t)(void*)&lf4[i * 64], 16, 0, 0);
        __builtin_amdgcn_global_load_lds((gas_t)(const void*)(gm4 + idx),
                                         (las_t)(void*)&lm4[i * 64], 16, 0, 0);
    }

    // ---- these overlap the DMA backlog ----
    const float dt = dt_ptr[0];   // 0.125
    const int wl = (lane < NPZD_QW) ? lane : (NPZD_QW - 1);   // local week
    const int wg = NPZD_QW * qb + wl;                          // global week
    const float* xb = X_in + ((size_t)b * NPZD_WK + wg) * 5;
    float N = xb[1], P = xb[2], Z = xb[3], D = xb[4];

    const float* pp = params + (size_t)b * 10;   // block-uniform -> s_load
    const float chi   = pp[0];
    const float rho2  = pp[1] * 2.0f;
    const float gam1  = pp[2] * 0.1f;
    const float lam05 = pp[3] * 0.05f;
    const float eps1  = pp[4] * 0.1f;
    const float alp3  = pp[5] * 0.3f;
    const float bet6  = pp[6] * 0.6f;
    const float eta15 = pp[7] * 0.15f;
    const float phi4  = pp[8] * 0.4f;
    const float zet1  = pp[9] * 0.1f;
    const float rem   = 1.0f - alp3 - bet6;

    __syncthreads();   // compiler emits s_waitcnt vmcnt(0) before s_barrier

    // ---- integrate: lanes 0..12, one trajectory each, raw-image reads ----
    if (lane >= NPZD_QW) return;

    float oN[8], oP[8], oZ[8], oD[8];
    oN[0] = N; oP[0] = P; oZ[0] = Z; oD[0] = D;

    // week wl starts at image word 168*wl (global f4 42*wg = 546*qb + 42*wl);
    // step s uses word 168*wl + 3*s (hour 168*wg + 3s), R10-proven.
    const float* lf = (const float*)lf4 + 168 * wl;
    const float* lm = (const float*)lm4 + 168 * wl;

    #pragma unroll
    for (int g = 0; g < 14; ++g) {
        #pragma unroll
        for (int q = 0; q < 4; ++q) {
            const int s = 4 * g + q;
            const float ft = lf[3 * s];
            const float mt = lm[3 * s];
            const float Pc = fmaxf(0.01f, P);
            const float Zc = fmaxf(0.01f, Z);
            const float gN = N * __builtin_amdgcn_rcpf(chi + N);
            const float zg = rho2 * (1.0f - __expf(-lam05 * Pc)) * Zc;
            const float up = gN * ft * Pc;
            const float Nn = N + dt * (-up + alp3 * zg + eps1 * P + gam1 * Z + phi4 * D + mt * (8.0f - N));
            const float Pn = P + dt * (up - zg - eps1 * P - eta15 * P - mt * P);
            const float Zn = Z + dt * (bet6 * zg - gam1 * Z - mt * Z);
            const float Dn = D + dt * (eta15 * P + rem * zg - phi4 * D - zet1 * D - mt * D);
            N = Nn; P = Pn; Z = Zn; D = Dn;
        }
        if (g & 1) {   // after steps 7,15,...,55
            const int c = (g >> 1) + 1;
            oN[c] = N; oP[c] = P; oZ[c] = Z; oD[c] = D;
        }
    }

    // ---- output: (b, wg, state, 8) -> 32 contiguous floats per trajectory ----
    f32x4* o4 = (f32x4*)(out + ((size_t)b * NPZD_WK + wg) * 32);
    o4[0] = (f32x4){oN[0], oN[1], oN[2], oN[3]};
    o4[1] = (f32x4){oN[4], oN[5], oN[6], oN[7]};
    o4[2] = (f32x4){oP[0], oP[1], oP[2], oP[3]};
    o4[3] = (f32x4){oP[4], oP[5], oP[6], oP[7]};
    o4[4] = (f32x4){oZ[0], oZ[1], oZ[2], oZ[3]};
    o4[5] = (f32x4){oZ[4], oZ[5], oZ[6], oZ[7]};
    o4[6] = (f32x4){oD[0], oD[1], oD[2], oD[3]};
    o4[7] = (f32x4){oD[4], oD[5], oD[6], oD[7]};
}

extern "C" void kernel_launch(void* const* d_in, const int* in_sizes, int n_in,
                              void* d_out, int out_size, void* d_ws, size_t ws_size,
                              hipStream_t stream) {
    const float* X_in   = (const float*)d_in[0];
    const float* gf     = (const float*)d_in[1];
    const float* gm     = (const float*)d_in[2];
    const float* params = (const float*)d_in[3];
    const float* dt_ptr = (const float*)d_in[4];
    float* out = (float*)d_out;

    npzd_kernel<<<NPZD_B * 4, 64, 0, stream>>>(X_in, gf, gm, params, dt_ptr, out);
}